// Round 5
// baseline (296.724 us; speedup 1.0000x reference)
//
#include <hip/hip_runtime.h>

constexpr int Bn  = 1024;
constexpr int Tn  = 8192;
constexpr int Wn  = 2048;   // NUM_WORDS

// ---- plan B (split rows) config ----
constexpr int QP   = 4;            // quarter-row blocks per row
constexpr int SEG  = Tn / QP;      // 2048 positions per block
constexpr int TPB1 = 256;          // 4 waves
constexpr int TPB2 = 256;

// ws layout (bytes):
//   0:  float acc_pdur; 4: acc_rules; 8: acc_wd; 12: acc_sd; 16: uint cnt2
//   64: float sprow[Bn]; 64+4096: float sgrow[Bn]
//   16384: float wp_g[Bn*Wn]; +8MB: float wg_g[Bn*Wn]
constexpr size_t OFF_SPROW = 64;
constexpr size_t OFF_SGROW = 64 + 4096;
constexpr size_t OFF_WP    = 16384;
constexpr size_t OFF_WG    = OFF_WP + (size_t)Bn * Wn * 4;
constexpr size_t WS_NEEDED = OFF_WG + (size_t)Bn * Wn * 4;

// Per-position rule evaluation (matches the vectorized reference exactly)
__device__ __forceinline__ void rule_eval(float dp, float dpn, int tok, bool valid_next,
                                          float& g1, float& g2, float& sa) {
  float expected;
  bool in_init = true;
  switch (tok) {
    case 94:  expected = 2.f; break;
    case 122: expected = 3.f; break;
    case 100: expected = 2.f; break;
    case 92:  expected = 2.f; break;
    case 43:  expected = 5.f; break;
    case 27:  expected = 5.f; break;
    default:  expected = 0.f; in_init = false; break;
  }
  float t1 = dp - expected;
  bool fire1 = in_init && (t1 > 0.f);
  g1 = fire1 ? t1 : 0.f;
  bool in_ratio = (tok == 44) | (tok == 28) | (tok == 29) |
                  (tok == 27) | (tok == 121) | (tok == 43);
  bool fire2 = in_ratio && valid_next && (3.f * dp > dpn);
  g2 = fire2 ? (dp - dpn * (1.f / 3.f)) : 0.f;
  sa = fire2 ? g2 : (fire1 ? g1 : 0.f);
}

__device__ __forceinline__ float wave_reduce(float v) {
  #pragma unroll
  for (int o = 32; o > 0; o >>= 1) v += __shfl_down(v, o, 64);
  return v;
}

// ---------------- kernel 1: quarter-row elementwise + word hist ----------------
__global__ __launch_bounds__(TPB1, 8) void k1_elem(
    const float* __restrict__ dur_pred, const float* __restrict__ dur_gt,
    const int* __restrict__ ph2word, const int* __restrict__ txt,
    char* __restrict__ ws)
{
  __shared__ float wp[Wn];
  __shared__ float wg[Wn];
  __shared__ float sacc[4];   // pdur, rules, sp, sg

  float* acc_pdur  = (float*)(ws + 0);
  float* acc_rules = (float*)(ws + 4);
  float* sprow     = (float*)(ws + OFF_SPROW);
  float* sgrow     = (float*)(ws + OFF_SGROW);
  float* wp_g      = (float*)(ws + OFF_WP);
  float* wg_g      = (float*)(ws + OFF_WG);

  const int bid = blockIdx.x;
  const int row = bid >> 2;
  const int q   = bid & 3;
  const size_t roff = (size_t)row * Tn;
  const float* __restrict__ dpr = dur_pred + roff;
  const float* __restrict__ dgr = dur_gt + roff;
  const int*   __restrict__ pwr = ph2word + roff;
  const int*   __restrict__ tkr = txt + roff;

  for (int i = threadIdx.x; i < Wn; i += TPB1) { wp[i] = 0.f; wg[i] = 0.f; }
  if (threadIdx.x < 4) sacc[threadIdx.x] = 0.f;
  __syncthreads();

  float pdur_s = 0.f, rules_s = 0.f, sp = 0.f, sg = 0.f;

  #pragma unroll
  for (int c = 0; c < 2; ++c) {
    const int base = q * SEG + c * (SEG / 2) + threadIdx.x * 4;

    float4 dp4 = *reinterpret_cast<const float4*>(dpr + base);
    float4 dg4 = *reinterpret_cast<const float4*>(dgr + base);
    int4   pw4 = *reinterpret_cast<const int4*>(pwr + base);
    int4   tk4 = *reinterpret_cast<const int4*>(tkr + base);

    const bool last = (base + 4 >= Tn);   // only final thread of final quarter

    float dpx[6];
    dpx[0] = dp4.x; dpx[1] = dp4.y; dpx[2] = dp4.z; dpx[3] = dp4.w;
    dpx[4] = last ? 0.f : dpr[base + 4];
    dpx[5] = (base + 5 < Tn) ? dpr[base + 5] : 0.f;
    int tkx[5];
    tkx[0] = tk4.x; tkx[1] = tk4.y; tkx[2] = tk4.z; tkx[3] = tk4.w;
    tkx[4] = last ? -1 : tkr[base + 4];

    float g1[5], g2[5], sa[5];
    #pragma unroll
    for (int j = 0; j < 5; ++j) {
      int i = base + j;
      rule_eval(dpx[j], dpx[j + 1], tkx[j], i < Tn - 1, g1[j], g2[j], sa[j]);
    }

    float dgl[4] = {dg4.x, dg4.y, dg4.z, dg4.w};

    #pragma unroll
    for (int j = 0; j < 4; ++j) {
      int i = base + j;
      float dp = dpx[j];
      float add = (i < Tn - 1) ? (g1[j + 1] + g2[j + 1]) : 0.f;
      float dr = dp - sa[j] + add;            // dur_rules[i]
      float lp = __logf(dp + 1.f);
      float dlr = lp - __logf(dr + 1.f);
      rules_s += dlr * dlr;
      float dlg = lp - __logf(dgl[j] + 1.f);
      pdur_s += dlg * dlg;
      sp += fmaxf(dp, 0.f);
      sg += dgl[j];
    }

    // word segment sums: sorted -> run-compress, LDS atomics
    int pwl[4] = {pw4.x, pw4.y, pw4.z, pw4.w};
    int curw = pwl[0];
    float ap = 0.f, ag = 0.f;
    #pragma unroll
    for (int j = 0; j < 4; ++j) {
      if (pwl[j] != curw) {
        atomicAdd(&wp[curw], ap);
        atomicAdd(&wg[curw], ag);
        curw = pwl[j]; ap = 0.f; ag = 0.f;
      }
      ap += fmaxf(dpx[j], 0.f);
      ag += dgl[j];
    }
    atomicAdd(&wp[curw], ap);
    atomicAdd(&wg[curw], ag);
  }

  __syncthreads();

  // flush block-local word hist to per-row global arrays (fire-and-forget)
  {
    float* wpg = wp_g + (size_t)row * Wn;
    float* wgg = wg_g + (size_t)row * Wn;
    for (int w = threadIdx.x; w < Wn; w += TPB1) {
      float vp = wp[w], vg = wg[w];
      if (vp != 0.f) atomicAdd(&wpg[w], vp);
      if (vg != 0.f) atomicAdd(&wgg[w], vg);
    }
  }

  pdur_s  = wave_reduce(pdur_s);
  rules_s = wave_reduce(rules_s);
  sp      = wave_reduce(sp);
  sg      = wave_reduce(sg);
  if ((threadIdx.x & 63) == 0) {
    atomicAdd(&sacc[0], pdur_s);
    atomicAdd(&sacc[1], rules_s);
    atomicAdd(&sacc[2], sp);
    atomicAdd(&sacc[3], sg);
  }
  __syncthreads();

  if (threadIdx.x == 0) {
    atomicAdd(acc_pdur,  sacc[0]);
    atomicAdd(acc_rules, sacc[1]);
    atomicAdd(&sprow[row], sacc[2]);
    atomicAdd(&sgrow[row], sacc[3]);
  }
}

// ---------------- kernel 2: word loss + sentence loss + finalize ----------------
__global__ __launch_bounds__(TPB2) void k2_word(char* __restrict__ ws,
                                                float* __restrict__ out)
{
  __shared__ float swd[1];

  float* acc_pdur  = (float*)(ws + 0);
  float* acc_rules = (float*)(ws + 4);
  float* acc_wd    = (float*)(ws + 8);
  float* acc_sd    = (float*)(ws + 12);
  unsigned int* cnt2 = (unsigned int*)(ws + 16);
  float* sprow     = (float*)(ws + OFF_SPROW);
  float* sgrow     = (float*)(ws + OFF_SGROW);
  const float* wp_g = (const float*)(ws + OFF_WP);
  const float* wg_g = (const float*)(ws + OFF_WG);

  const int r = blockIdx.x;
  const float* __restrict__ wpr = wp_g + (size_t)r * Wn;
  const float* __restrict__ wgr = wg_g + (size_t)r * Wn;

  if (threadIdx.x == 0) swd[0] = 0.f;
  __syncthreads();

  float wd_s = 0.f;
  for (int w = threadIdx.x; w < Wn; w += TPB2) {
    if (w != 0) {
      float d = __logf(wpr[w] + 1.f) - __logf(wgr[w] + 1.f);
      wd_s += d * d;
    }
  }
  wd_s = wave_reduce(wd_s);
  if ((threadIdx.x & 63) == 0) atomicAdd(&swd[0], wd_s);
  __syncthreads();

  if (threadIdx.x == 0) {
    atomicAdd(acc_wd, swd[0]);
    float ds = __logf(sprow[r] + 1.f) - __logf(sgrow[r] + 1.f);
    atomicAdd(acc_sd, ds * ds);
    __threadfence();
    unsigned int t = atomicAdd(cnt2, 1u);
    if (t == (unsigned int)(Bn - 1)) {
      float pd = atomicAdd(acc_pdur, 0.f);
      float rl = atomicAdd(acc_rules, 0.f);
      float wd = atomicAdd(acc_wd, 0.f);
      float sd = atomicAdd(acc_sd, 0.f);
      double total = 0.6 * (double)pd / ((double)Bn * (double)Tn)
                   + 0.3 * (double)rl / ((double)Bn * (double)Tn)
                   + 0.3 * (double)wd / ((double)Bn * (double)(Wn - 1))
                   + 0.1 * (double)sd / (double)Bn;
      out[0] = (float)total;
    }
  }
}

// ---------------- fallback: proven R1 single-row kernel ----------------
__global__ __launch_bounds__(1024) void loss_kernel_full(
    const float* __restrict__ dur_pred, const float* __restrict__ dur_gt,
    const int* __restrict__ ph2word, const int* __restrict__ txt,
    double* __restrict__ acc)
{
  __shared__ float wp[Wn];
  __shared__ float wg[Wn];
  __shared__ float sacc[5];

  const int row = blockIdx.x;
  const size_t roff = (size_t)row * Tn;
  const float* __restrict__ dpr = dur_pred + roff;
  const float* __restrict__ dgr = dur_gt + roff;
  const int*   __restrict__ pwr = ph2word + roff;
  const int*   __restrict__ tkr = txt + roff;

  for (int i = threadIdx.x; i < Wn; i += 1024) { wp[i] = 0.f; wg[i] = 0.f; }
  if (threadIdx.x < 5) sacc[threadIdx.x] = 0.f;
  __syncthreads();

  float pdur_s = 0.f, rules_s = 0.f, sp = 0.f, sg = 0.f;

  #pragma unroll
  for (int c = 0; c < 2; ++c) {
    const int base = c * (Tn / 2) + threadIdx.x * 4;
    float4 dp4 = *reinterpret_cast<const float4*>(dpr + base);
    float4 dg4 = *reinterpret_cast<const float4*>(dgr + base);
    int4   pw4 = *reinterpret_cast<const int4*>(pwr + base);
    int4   tk4 = *reinterpret_cast<const int4*>(tkr + base);
    const bool last = (base + 4 >= Tn);
    float dpx[6];
    dpx[0] = dp4.x; dpx[1] = dp4.y; dpx[2] = dp4.z; dpx[3] = dp4.w;
    dpx[4] = last ? 0.f : dpr[base + 4];
    dpx[5] = (base + 5 < Tn) ? dpr[base + 5] : 0.f;
    int tkx[5];
    tkx[0] = tk4.x; tkx[1] = tk4.y; tkx[2] = tk4.z; tkx[3] = tk4.w;
    tkx[4] = last ? -1 : tkr[base + 4];
    float g1[5], g2[5], sa[5];
    #pragma unroll
    for (int j = 0; j < 5; ++j) {
      int i = base + j;
      rule_eval(dpx[j], dpx[j + 1], tkx[j], i < Tn - 1, g1[j], g2[j], sa[j]);
    }
    float dgl[4] = {dg4.x, dg4.y, dg4.z, dg4.w};
    #pragma unroll
    for (int j = 0; j < 4; ++j) {
      int i = base + j;
      float dp = dpx[j];
      float add = (i < Tn - 1) ? (g1[j + 1] + g2[j + 1]) : 0.f;
      float dr = dp - sa[j] + add;
      float lp = __logf(dp + 1.f);
      float dlr = lp - __logf(dr + 1.f);
      rules_s += dlr * dlr;
      float dlg = lp - __logf(dgl[j] + 1.f);
      pdur_s += dlg * dlg;
      sp += fmaxf(dp, 0.f);
      sg += dgl[j];
    }
    int pwl[4] = {pw4.x, pw4.y, pw4.z, pw4.w};
    int curw = pwl[0];
    float ap = 0.f, ag = 0.f;
    #pragma unroll
    for (int j = 0; j < 4; ++j) {
      if (pwl[j] != curw) {
        atomicAdd(&wp[curw], ap);
        atomicAdd(&wg[curw], ag);
        curw = pwl[j]; ap = 0.f; ag = 0.f;
      }
      ap += fmaxf(dpx[j], 0.f);
      ag += dgl[j];
    }
    atomicAdd(&wp[curw], ap);
    atomicAdd(&wg[curw], ag);
  }

  __syncthreads();

  float wd_s = 0.f;
  for (int w = threadIdx.x; w < Wn; w += 1024) {
    if (w != 0) {
      float d = __logf(wp[w] + 1.f) - __logf(wg[w] + 1.f);
      wd_s += d * d;
    }
  }

  pdur_s  = wave_reduce(pdur_s);
  rules_s = wave_reduce(rules_s);
  sp      = wave_reduce(sp);
  sg      = wave_reduce(sg);
  wd_s    = wave_reduce(wd_s);
  if ((threadIdx.x & 63) == 0) {
    atomicAdd(&sacc[0], pdur_s);
    atomicAdd(&sacc[1], rules_s);
    atomicAdd(&sacc[2], sp);
    atomicAdd(&sacc[3], sg);
    atomicAdd(&sacc[4], wd_s);
  }
  __syncthreads();

  if (threadIdx.x == 0) {
    float ds = __logf(sacc[2] + 1.f) - __logf(sacc[3] + 1.f);
    double total = 0.6 * (double)sacc[0] / ((double)Bn * (double)Tn)
                 + 0.3 * (double)sacc[1] / ((double)Bn * (double)Tn)
                 + 0.3 * (double)sacc[4] / ((double)Bn * (double)(Wn - 1))
                 + 0.1 * (double)(ds * ds) / (double)Bn;
    atomicAdd(acc, total);
  }
}

__global__ void finalize_kernel(const double* __restrict__ acc, float* __restrict__ out) {
  out[0] = (float)(*acc);
}

extern "C" void kernel_launch(void* const* d_in, const int* in_sizes, int n_in,
                              void* d_out, int out_size, void* d_ws, size_t ws_size,
                              hipStream_t stream) {
  const float* dur_pred = (const float*)d_in[0];
  const float* dur_gt   = (const float*)d_in[1];
  const int*   ph2word  = (const int*)d_in[2];
  const int*   txt      = (const int*)d_in[3];

  if (ws_size >= WS_NEEDED) {
    hipMemsetAsync(d_ws, 0, WS_NEEDED, stream);
    k1_elem<<<Bn * QP, TPB1, 0, stream>>>(dur_pred, dur_gt, ph2word, txt,
                                          (char*)d_ws);
    k2_word<<<Bn, TPB2, 0, stream>>>((char*)d_ws, (float*)d_out);
  } else {
    double* acc = (double*)d_ws;
    hipMemsetAsync(d_ws, 0, sizeof(double), stream);
    loss_kernel_full<<<Bn, 1024, 0, stream>>>(dur_pred, dur_gt, ph2word, txt, acc);
    finalize_kernel<<<1, 1, 0, stream>>>(acc, (float*)d_out);
  }
}

// Round 6
// 198.125 us; speedup vs baseline: 1.4977x; 1.4977x over previous
//
#include <hip/hip_runtime.h>

constexpr int Bn  = 1024;
constexpr int Tn  = 8192;
constexpr int Wn  = 2048;   // NUM_WORDS
constexpr int TPB = 512;
constexpr int CH  = 4;               // chunks per thread (processed in pairs)
constexpr int STRIDE = Tn / CH;      // 2048 elements per chunk region

// Per-position rule evaluation (matches the vectorized reference exactly):
//   INIT_TOKENS  = {94,122,100,92,43,27} -> INIT_DURS {2,3,2,2,5,5}
//   RATIO_TOKENS = {44,28,29,27,121,43}
__device__ __forceinline__ void rule_eval(float dp, float dpn, int tok, bool valid_next,
                                          float& g1, float& g2, float& sa) {
  float expected;
  bool in_init = true;
  switch (tok) {
    case 94:  expected = 2.f; break;
    case 122: expected = 3.f; break;
    case 100: expected = 2.f; break;
    case 92:  expected = 2.f; break;
    case 43:  expected = 5.f; break;
    case 27:  expected = 5.f; break;
    default:  expected = 0.f; in_init = false; break;
  }
  float t1 = dp - expected;
  bool fire1 = in_init && (t1 > 0.f);
  g1 = fire1 ? t1 : 0.f;
  bool in_ratio = (tok == 44) | (tok == 28) | (tok == 29) |
                  (tok == 27) | (tok == 121) | (tok == 43);
  bool fire2 = in_ratio && valid_next && (3.f * dp > dpn);
  g2 = fire2 ? (dp - dpn * (1.f / 3.f)) : 0.f;
  sa = fire2 ? g2 : (fire1 ? g1 : 0.f);
}

__device__ __forceinline__ float wave_reduce(float v) {
  #pragma unroll
  for (int o = 32; o > 0; o >>= 1) v += __shfl_down(v, o, 64);
  return v;
}

__global__ __launch_bounds__(TPB, 4) void loss_kernel(
    const float* __restrict__ dur_pred, const float* __restrict__ dur_gt,
    const int* __restrict__ ph2word, const int* __restrict__ txt,
    double* __restrict__ acc, unsigned int* __restrict__ cnt,
    float* __restrict__ out)
{
  __shared__ float wp[Wn];
  __shared__ float wg[Wn];
  __shared__ float sacc[5];   // pdur_s, rules_s, sp, sg, wd_s

  const int row = blockIdx.x;
  const size_t roff = (size_t)row * Tn;
  const float* __restrict__ dpr = dur_pred + roff;
  const float* __restrict__ dgr = dur_gt + roff;
  const int*   __restrict__ pwr = ph2word + roff;
  const int*   __restrict__ tkr = txt + roff;

  for (int i = threadIdx.x; i < Wn; i += TPB) { wp[i] = 0.f; wg[i] = 0.f; }
  if (threadIdx.x < 5) sacc[threadIdx.x] = 0.f;
  __syncthreads();

  float pdur_s = 0.f, rules_s = 0.f, sp = 0.f, sg = 0.f;

  // Processes one 4-element chunk held entirely in registers.
  auto process = [&](float4 dp4, float4 dg4, int4 pw4, int4 tk4,
                     float t0, float t1v, int tt, int base) {
    const bool last = (base + 4 >= Tn);
    float dpx[6];
    dpx[0] = dp4.x; dpx[1] = dp4.y; dpx[2] = dp4.z; dpx[3] = dp4.w;
    dpx[4] = last ? 0.f : t0;
    dpx[5] = last ? 0.f : t1v;
    int tkx[5];
    tkx[0] = tk4.x; tkx[1] = tk4.y; tkx[2] = tk4.z; tkx[3] = tk4.w;
    tkx[4] = last ? -1 : tt;

    float g1[5], g2[5], sa[5];
    #pragma unroll
    for (int j = 0; j < 5; ++j) {
      int i = base + j;
      rule_eval(dpx[j], dpx[j + 1], tkx[j], i < Tn - 1, g1[j], g2[j], sa[j]);
    }

    float dgl[4] = {dg4.x, dg4.y, dg4.z, dg4.w};

    #pragma unroll
    for (int j = 0; j < 4; ++j) {
      int i = base + j;
      float dp = dpx[j];
      float add = (i < Tn - 1) ? (g1[j + 1] + g2[j + 1]) : 0.f;
      float dr = dp - sa[j] + add;            // dur_rules[i]
      float lp = __logf(dp + 1.f);
      float dlr = lp - __logf(dr + 1.f);
      rules_s += dlr * dlr;
      float dlg = lp - __logf(dgl[j] + 1.f);
      pdur_s += dlg * dlg;
      sp += fmaxf(dp, 0.f);
      sg += dgl[j];
    }

    // word segment sums: ph2word sorted per row -> run-compress, LDS atomics
    int pwl[4] = {pw4.x, pw4.y, pw4.z, pw4.w};
    int curw = pwl[0];
    float ap = 0.f, ag = 0.f;
    #pragma unroll
    for (int j = 0; j < 4; ++j) {
      if (pwl[j] != curw) {
        atomicAdd(&wp[curw], ap);
        atomicAdd(&wg[curw], ag);
        curw = pwl[j]; ap = 0.f; ag = 0.f;
      }
      ap += fmaxf(dpx[j], 0.f);
      ag += dgl[j];
    }
    atomicAdd(&wp[curw], ap);
    atomicAdd(&wg[curw], ag);
  };

  // Two super-iterations; each loads TWO chunks (8+ vector loads in flight),
  // then computes both. unroll 1 keeps only one pair's buffers live.
  #pragma unroll 1
  for (int s = 0; s < CH / 2; ++s) {
    const int bA = (2 * s) * STRIDE + threadIdx.x * 4;
    const int bB = (2 * s + 1) * STRIDE + threadIdx.x * 4;

    float4 dpA = *reinterpret_cast<const float4*>(dpr + bA);
    float4 dgA = *reinterpret_cast<const float4*>(dgr + bA);
    int4   pwA = *reinterpret_cast<const int4*>(pwr + bA);
    int4   tkA = *reinterpret_cast<const int4*>(tkr + bA);
    float4 dpB = *reinterpret_cast<const float4*>(dpr + bB);
    float4 dgB = *reinterpret_cast<const float4*>(dgr + bB);
    int4   pwB = *reinterpret_cast<const int4*>(pwr + bB);
    int4   tkB = *reinterpret_cast<const int4*>(tkr + bB);

    // neighbor tails (clamped index; 'last' flag in process() masks misuse)
    const int eA0 = (bA + 4 < Tn) ? bA + 4 : Tn - 1;
    const int eA1 = (bA + 5 < Tn) ? bA + 5 : Tn - 1;
    const int eB0 = (bB + 4 < Tn) ? bB + 4 : Tn - 1;
    const int eB1 = (bB + 5 < Tn) ? bB + 5 : Tn - 1;
    float tA0 = dpr[eA0], tA1 = dpr[eA1];
    int   tAt = tkr[eA0];
    float tB0 = dpr[eB0], tB1 = dpr[eB1];
    int   tBt = tkr[eB0];

    process(dpA, dgA, pwA, tkA, tA0, tA1, tAt, bA);
    process(dpB, dgB, pwB, tkB, tB0, tB1, tBt, bB);
  }

  __syncthreads();

  // word-duration loss over words 1..Wn-1 (segment 0 dropped)
  float wd_s = 0.f;
  #pragma unroll
  for (int w = threadIdx.x; w < Wn; w += TPB) {
    if (w != 0) {
      float d = __logf(wp[w] + 1.f) - __logf(wg[w] + 1.f);
      wd_s += d * d;
    }
  }

  pdur_s  = wave_reduce(pdur_s);
  rules_s = wave_reduce(rules_s);
  sp      = wave_reduce(sp);
  sg      = wave_reduce(sg);
  wd_s    = wave_reduce(wd_s);
  if ((threadIdx.x & 63) == 0) {
    atomicAdd(&sacc[0], pdur_s);
    atomicAdd(&sacc[1], rules_s);
    atomicAdd(&sacc[2], sp);
    atomicAdd(&sacc[3], sg);
    atomicAdd(&sacc[4], wd_s);
  }
  __syncthreads();

  if (threadIdx.x == 0) {
    float ds = __logf(sacc[2] + 1.f) - __logf(sacc[3] + 1.f);
    double total = 0.6 * (double)sacc[0] / ((double)Bn * (double)Tn)
                 + 0.3 * (double)sacc[1] / ((double)Bn * (double)Tn)
                 + 0.3 * (double)sacc[4] / ((double)Bn * (double)(Wn - 1))
                 + 0.1 * (double)(ds * ds) / (double)Bn;
    atomicAdd(acc, total);
    __threadfence();
    unsigned int ticket = atomicAdd(cnt, 1u);
    if (ticket == (unsigned int)(Bn - 1)) {
      double final_val = atomicAdd(acc, 0.0);
      out[0] = (float)final_val;
    }
  }
}

extern "C" void kernel_launch(void* const* d_in, const int* in_sizes, int n_in,
                              void* d_out, int out_size, void* d_ws, size_t ws_size,
                              hipStream_t stream) {
  const float* dur_pred = (const float*)d_in[0];
  const float* dur_gt   = (const float*)d_in[1];
  const int*   ph2word  = (const int*)d_in[2];
  const int*   txt      = (const int*)d_in[3];
  double* acc = (double*)d_ws;
  unsigned int* cnt = (unsigned int*)((char*)d_ws + sizeof(double));

  hipMemsetAsync(d_ws, 0, 16, stream);
  loss_kernel<<<Bn, TPB, 0, stream>>>(dur_pred, dur_gt, ph2word, txt, acc, cnt,
                                      (float*)d_out);
}